// Round 7
// baseline (895.365 us; speedup 1.0000x reference)
//
#include <hip/hip_runtime.h>
#include <hip/hip_bf16.h>
#include <math.h>

#define NFULL 1024
#define CDIM  512
#define HD    64
#define NH    8

typedef __attribute__((ext_vector_type(8))) short s16x8;
typedef __attribute__((ext_vector_type(4))) short s16x4;
typedef __attribute__((ext_vector_type(4))) float f32x4;

__device__ __forceinline__ float b2f(unsigned short u) {
  return __uint_as_float((unsigned)u << 16);
}
__device__ __forceinline__ unsigned short f2b(float f) {
  unsigned u = __float_as_uint(f);
  return (unsigned short)((u + 0x7FFFu + ((u >> 16) & 1u)) >> 16);
}

// ---------------- piecewise bucket index ----------------
__device__ __forceinline__ int pwidx(int d) {
  int ad = d < 0 ? -d : d;
  if (ad <= 1) return d;
  float v = 1.9f + logf((float)ad * (1.0f / 1.9f)) * (1.9f / 2.0794415416798357f); // ln(8)
  v = fminf(v, 3.8f);
  int m = (int)rintf(v);
  if (m > 4) m = 4;
  return d > 0 ? m : -m;
}

// ---------------- layernorm -> bf16 ----------------
__global__ __launch_bounds__(256) void ln_kernel(const float* __restrict__ x,
                                                 const float* __restrict__ g,
                                                 const float* __restrict__ be,
                                                 __hip_bfloat16* __restrict__ y) {
  __shared__ float red[8];
  int row = blockIdx.x, tid = threadIdx.x;
  const float* xr = x + (size_t)row * CDIM;
  float v0 = xr[tid], v1 = xr[tid + 256];
  float s = v0 + v1;
#pragma unroll
  for (int off = 32; off; off >>= 1) s += __shfl_xor(s, off);
  int wid = tid >> 6, lane = tid & 63;
  if (!lane) red[wid] = s;
  __syncthreads();
  float mu = (red[0] + red[1] + red[2] + red[3]) * (1.0f / 512.0f);
  float d0 = v0 - mu, d1 = v1 - mu;
  float q = d0 * d0 + d1 * d1;
#pragma unroll
  for (int off = 32; off; off >>= 1) q += __shfl_xor(q, off);
  if (!lane) red[4 + wid] = q;
  __syncthreads();
  float var = (red[4] + red[5] + red[6] + red[7]) * (1.0f / 512.0f);
  float rstd = rsqrtf(var + 1e-5f);
  __hip_bfloat16* yr = y + (size_t)row * CDIM;
  yr[tid]       = __float2bfloat16(d0 * rstd * g[tid]       + be[tid]);
  yr[tid + 256] = __float2bfloat16(d1 * rstd * g[tid + 256] + be[tid + 256]);
}

// ---------------- weight transpose + bf16 cast ----------------
__global__ __launch_bounds__(256) void wtrans_kernel(const float* __restrict__ W,
                                                     __hip_bfloat16* __restrict__ Wt,
                                                     int K, int N) {
  __shared__ float t[32][33];
  int n0 = blockIdx.x * 32, k0 = blockIdx.y * 32;
  int c = threadIdx.x, r0 = threadIdx.y;
#pragma unroll
  for (int rr = 0; rr < 32; rr += 8) t[r0 + rr][c] = W[(size_t)(k0 + r0 + rr) * N + n0 + c];
  __syncthreads();
#pragma unroll
  for (int rr = 0; rr < 32; rr += 8)
    Wt[(size_t)(n0 + r0 + rr) * K + k0 + c] = __float2bfloat16(t[c][r0 + rr]);
}

__device__ __forceinline__ float gelu_f(float x) {
  return 0.5f * x * (1.0f + erff(x * 0.7071067811865475f));
}

// ---------------- bf16 MFMA GEMM (verified R4/R5) ----------------
template <int ACT, int RES, int OUTBF>
__global__ __launch_bounds__(256, 1) void gemm_bf16(const short* __restrict__ A,
                                                    const short* __restrict__ Bt,
                                                    const float* __restrict__ bias,
                                                    const float* __restrict__ res,
                                                    void* __restrict__ Cout,
                                                    int M, int N, int K) {
  __shared__ __attribute__((aligned(16))) short As[128 * 40];
  __shared__ __attribute__((aligned(16))) short Bs[128 * 40];
  const int tid = threadIdx.x;
  const int bm = blockIdx.y * 128, bn = blockIdx.x * 128;
  const int w = tid >> 6, l = tid & 63;
  const int wr = w >> 1, wc = w & 1;
  const int lr = l & 15, lg = l >> 4;
  const int sr = tid >> 1, sh = (tid & 1) * 16;

  f32x4 acc[4][4] = {};

  for (int k0 = 0; k0 < K; k0 += 32) {
    __syncthreads();
    const float4* ga = (const float4*)(A + (size_t)(bm + sr) * K + k0 + sh);
    const float4* gb = (const float4*)(Bt + (size_t)(bn + sr) * K + k0 + sh);
    float4 a0 = ga[0], a1 = ga[1];
    float4 b0 = gb[0], b1 = gb[1];
    *(float4*)&As[sr * 40 + sh]     = a0;
    *(float4*)&As[sr * 40 + sh + 8] = a1;
    *(float4*)&Bs[sr * 40 + sh]     = b0;
    *(float4*)&Bs[sr * 40 + sh + 8] = b1;
    __syncthreads();
    s16x8 af[4], bf[4];
#pragma unroll
    for (int mi = 0; mi < 4; ++mi)
      af[mi] = *(const s16x8*)&As[(wr * 64 + mi * 16 + lr) * 40 + lg * 8];
#pragma unroll
    for (int ni = 0; ni < 4; ++ni)
      bf[ni] = *(const s16x8*)&Bs[(wc * 64 + ni * 16 + lr) * 40 + lg * 8];
#pragma unroll
    for (int mi = 0; mi < 4; ++mi)
#pragma unroll
      for (int ni = 0; ni < 4; ++ni)
        acc[mi][ni] = __builtin_amdgcn_mfma_f32_16x16x32_bf16(af[mi], bf[ni], acc[mi][ni], 0, 0, 0);
  }
  float bv[4];
#pragma unroll
  for (int ni = 0; ni < 4; ++ni) bv[ni] = bias[bn + wc * 64 + ni * 16 + lr];
#pragma unroll
  for (int mi = 0; mi < 4; ++mi) {
#pragma unroll
    for (int j = 0; j < 4; ++j) {
      int row = bm + wr * 64 + mi * 16 + lg * 4 + j;
#pragma unroll
      for (int ni = 0; ni < 4; ++ni) {
        int col = bn + wc * 64 + ni * 16 + lr;
        float vv = acc[mi][ni][j] + bv[ni];
        if (ACT) vv = gelu_f(vv);
        if (RES) vv += res[(size_t)row * N + col];
        if (OUTBF) ((__hip_bfloat16*)Cout)[(size_t)row * N + col] = __float2bfloat16(vv);
        else       ((float*)Cout)[(size_t)row * N + col] = vv;
      }
    }
  }
}

// ---------------- prep: qkvb bf16 [4096][1536] -> Qb/Kb rows + Vt transposed ----------------
__global__ __launch_bounds__(256) void prep_kernel(const short* __restrict__ qkvb,
                                                   short* __restrict__ Qb,
                                                   short* __restrict__ Kb,
                                                   short* __restrict__ Vtb) {
  __shared__ short vlds[64 * 72];
  const int tid = threadIdx.x;
  const int n0 = blockIdx.x * 64;
  const int b = blockIdx.y;

#pragma unroll 4
  for (int it = 0; it < 32; ++it) {
    int e = tid + it * 256;
    int n = e >> 7, c8 = (e & 127) * 8;
    s16x8 v = *(const s16x8*)(qkvb + ((size_t)(b * NFULL + n0 + n)) * 1536 + c8);
    int hh = c8 >> 6, d8 = c8 & 63;
    if (hh < 8)
      *(s16x8*)(Qb + ((size_t)(b * 8 + hh) * NFULL + n0 + n) * 64 + d8) = v;
    else
      *(s16x8*)(Kb + ((size_t)(b * 8 + hh - 8) * NFULL + n0 + n) * 64 + d8) = v;
  }
  for (int hh = 0; hh < 8; ++hh) {
    __syncthreads();
#pragma unroll
    for (int rep = 0; rep < 2; ++rep) {
      int n = (tid >> 3) + rep * 32, d8 = (tid & 7) * 8;
      *(s16x8*)&vlds[n * 72 + d8] =
          *(const s16x8*)(qkvb + ((size_t)(b * NFULL + n0 + n)) * 1536 + 1024 + hh * 64 + d8);
    }
    __syncthreads();
#pragma unroll
    for (int rep = 0; rep < 2; ++rep) {
      int d = (tid >> 3) + rep * 32, n8 = (tid & 7) * 8;
      s16x8 o;
#pragma unroll
      for (int u = 0; u < 8; ++u) o[u] = vlds[(n8 + u) * 72 + d];
      *(s16x8*)(Vtb + ((size_t)(b * 8 + hh) * 64 + d) * NFULL + n0 + n8) = o;
    }
  }
}

// ---------------- bias GEMM (verified R5) ----------------
__global__ __launch_bounds__(256) void bias_gemm(const short* __restrict__ Xb,
                                                 const float* __restrict__ Tg,
                                                 short* __restrict__ outg,
                                                 float scl) {
  __shared__ __attribute__((aligned(16))) short tlds[96 * 88];
  const int tid = threadIdx.x;
  const int w = tid >> 6, l = tid & 63;
  const int g = l >> 4, i15 = l & 15;
  const int tile = blockIdx.x, h = blockIdx.y, b = blockIdx.z;
  const size_t bh = (size_t)(b * NH + h);

  for (int f = tid; f < 81 * 16; f += 256) {
    int c = f >> 4, d4 = (f & 15) * 4;
    float4 t4 = *(const float4*)&Tg[c * 64 + d4];
    s16x4 s4 = {(short)f2b(t4.x), (short)f2b(t4.y), (short)f2b(t4.z), (short)f2b(t4.w)};
    *(s16x4*)&tlds[c * 88 + d4] = s4;
  }
  __syncthreads();

  const int r0w = tile * 128 + w * 32;
  s16x8 af[2][2];
#pragma unroll
  for (int nk = 0; nk < 2; ++nk) {
    const short* xr = Xb + (bh * NFULL + r0w + nk * 16 + i15) * 64 + g * 8;
    af[nk][0] = *(const s16x8*)(xr);
    af[nk][1] = *(const s16x8*)(xr + 32);
  }
#pragma unroll
  for (int c0i = 0; c0i < 6; ++c0i) {
    int c0 = c0i * 16;
    s16x8 bf0 = *(const s16x8*)&tlds[(c0 + i15) * 88 + g * 8];
    s16x8 bf1 = *(const s16x8*)&tlds[(c0 + i15) * 88 + 32 + g * 8];
#pragma unroll
    for (int nk = 0; nk < 2; ++nk) {
      f32x4 acc = {0.f, 0.f, 0.f, 0.f};
      acc = __builtin_amdgcn_mfma_f32_16x16x32_bf16(af[nk][0], bf0, acc, 0, 0, 0);
      acc = __builtin_amdgcn_mfma_f32_16x16x32_bf16(af[nk][1], bf1, acc, 0, 0, 0);
      int c = c0 + i15;
      if (c < 81) {
#pragma unroll
        for (int r = 0; r < 4; ++r) {
          int n = r0w + nk * 16 + g * 4 + r;
          outg[(bh * NFULL + n) * 84 + c] = (short)f2b(acc[r] * scl);
        }
      }
    }
  }
}

// ---------------- MFMA attention v2: pipelined, LDS lk, early lq gathers ----------------
// One step of the 2-deep pipeline. All register arrays statically indexed.
#define ATTN_STEP(J0, J0N, KF, VF, KFN, VFN, BY0, BY1, BY0N, BY1N)                       \
  {                                                                                      \
    /* 1. lq gathers, issued before anything depends on them */                          \
    unsigned short lqv[4][4];                                                            \
    _Pragma("unroll") for (int jc = 0; jc < 4; ++jc) {                                   \
      _Pragma("unroll") for (int r = 0; r < 4; ++r) {                                    \
        int bb = ((jc & 2) ? (BY1) : (BY0)) + bx8[jc & 1][r];                            \
        lqv[jc][r] = lqb[(size_t)((J0) + jc * 16 + g * 4 + r) * 84 + 80 - bb];           \
      }                                                                                  \
    }                                                                                    \
    /* 2. S^T MFMA (K already in regs) */                                                \
    f32x4 sacc[4];                                                                       \
    _Pragma("unroll") for (int jc = 0; jc < 4; ++jc) {                                   \
      f32x4 zz = {0.f, 0.f, 0.f, 0.f};                                                   \
      sacc[jc] = __builtin_amdgcn_mfma_f32_16x16x32_bf16(KF[jc][0], qf0, zz, 0, 0, 0);   \
      sacc[jc] = __builtin_amdgcn_mfma_f32_16x16x32_bf16(KF[jc][1], qf1, sacc[jc], 0, 0, 0); \
    }                                                                                    \
    /* 3. prefetch next-tile K/V/by while S and lq are in flight */                      \
    {                                                                                    \
      int j0w = (J0N) & 1023;                                                            \
      _Pragma("unroll") for (int jc = 0; jc < 4; ++jc) {                                 \
        const short* kr = Kb_h + (size_t)(j0w + jc * 16 + i15) * 64 + g * 8;             \
        KFN[jc][0] = *(const s16x8*)(kr);                                                \
        KFN[jc][1] = *(const s16x8*)(kr + 32);                                           \
      }                                                                                  \
      _Pragma("unroll") for (int nc = 0; nc < 4; ++nc) {                                 \
        const short* vr = Vb_h + (size_t)(nc * 16 + i15) * NFULL + j0w + g * 8;          \
        VFN[nc][0] = *(const s16x8*)(vr);                                                \
        VFN[nc][1] = *(const s16x8*)(vr + 32);                                           \
      }                                                                                  \
      int jy0n = j0w >> 5;                                                               \
      BY0N = (int)pwy9s[iy - jy0n + 31];                                                 \
      BY1N = (int)pwy9s[iy - jy0n + 30];                                                 \
    }                                                                                    \
    /* 4. exp + pack P (bf16) */                                                         \
    s16x4 pvall[4];                                                                      \
    _Pragma("unroll") for (int jc = 0; jc < 4; ++jc) {                                   \
      s16x4 pv4;                                                                         \
      _Pragma("unroll") for (int r = 0; r < 4; ++r) {                                    \
        int bb = ((jc & 2) ? (BY1) : (BY0)) + bx8[jc & 1][r];                            \
        float sv = sacc[jc][r] * 0.125f + b2f(lkw[bb]) + b2f(lqv[jc][r]);                \
        float p = __expf(sv);                                                            \
        psum += p;                                                                       \
        pv4[r] = (short)f2b(p);                                                          \
      }                                                                                  \
      pvall[jc] = pv4;                                                                   \
      *(s16x4*)(pwc + i15 * 128 + ((jc * 32 + g * 8) ^ swz)) = pv4;                      \
    }                                                                                    \
    /* 5. PV MFMA */                                                                     \
    {                                                                                    \
      s16x8 pbf0 = *(const s16x8*)(pwc + i15 * 128 + ((16 * g) ^ swz));                  \
      s16x8 pbf1 = *(const s16x8*)(pwc + i15 * 128 + ((64 + 16 * g) ^ swz));             \
      _Pragma("unroll") for (int nc = 0; nc < 4; ++nc) {                                 \
        oacc[nc] = __builtin_amdgcn_mfma_f32_16x16x32_bf16(VF[nc][0], pbf0, oacc[nc], 0, 0, 0); \
        oacc[nc] = __builtin_amdgcn_mfma_f32_16x16x32_bf16(VF[nc][1], pbf1, oacc[nc], 0, 0, 0); \
      }                                                                                  \
    }                                                                                    \
    /* 6. histogram, off the critical path (uses packed bf16 p) */                       \
    _Pragma("unroll") for (int jc = 0; jc < 4; ++jc) {                                   \
      _Pragma("unroll") for (int r = 0; r < 4; ++r) {                                    \
        int bb = ((jc & 2) ? (BY1) : (BY0)) + bx8[jc & 1][r];                            \
        atomicAdd(&wbf[rowi * 81 + bb], b2f((unsigned short)pvall[jc][r]));              \
      }                                                                                  \
    }                                                                                    \
  }

__global__ __launch_bounds__(256, 3) void attn_mfma(const short* __restrict__ Qb,
                                                    const short* __restrict__ Kb,
                                                    const short* __restrict__ Vtb,
                                                    const short* __restrict__ lkg,
                                                    const short* __restrict__ lqg,
                                                    const float* __restrict__ tv,
                                                    __hip_bfloat16* __restrict__ o) {
  __shared__ __attribute__((aligned(16))) short lkb[64 * 84];   // 10.5 KB
  __shared__ __attribute__((aligned(16))) short pbuf[4][1024];  // 8 KB
  __shared__ float wbf[64 * 81];                                // 20.7 KB
  __shared__ short pwy9s[64], pwx4s[64];

  const int tid = threadIdx.x;
  const int w = tid >> 6, l = tid & 63;
  const int g = l >> 4, i15 = l & 15;
  // XCD-aware remap: all 16 i-tiles of one (b,h) share f%8 -> one XCD's L2
  const int f = blockIdx.x + 16 * (blockIdx.y + 8 * blockIdx.z);
  const int hb = f & 31, tile = f >> 5;
  const int b = hb >> 3, h = hb & 7;
  const int i0 = tile * 64;
  const size_t bh = (size_t)(b * NH + h);
  const int i = i0 + w * 16 + i15;
  const int rowi = w * 16 + i15;

  { // stage lk rows for this block + zero histogram + tables
    const s16x4* lksrc = (const s16x4*)(lkg + (bh * NFULL + i0) * 84);
    for (int ff = tid; ff < 1344; ff += 256) ((s16x4*)lkb)[ff] = lksrc[ff];
    for (int ff = tid; ff < 5184; ff += 256) wbf[ff] = 0.f;
    if (tid < 63) {
      int pv = pwidx(tid - 31);
      pwy9s[tid] = (short)((pv + 4) * 9);
      pwx4s[tid] = (short)(pv + 4);
    }
  }
  __syncthreads();

  const short* qrow = Qb + (bh * NFULL + i) * 64 + g * 8;
  const s16x8 qf0 = *(const s16x8*)(qrow);
  const s16x8 qf1 = *(const s16x8*)(qrow + 32);
  const short* Kb_h = Kb + bh * NFULL * 64;
  const short* Vb_h = Vtb + bh * 64 * NFULL;
  const unsigned short* lqb = (const unsigned short*)(lqg + bh * NFULL * 84);
  const unsigned short* lkw = (const unsigned short*)lkb + rowi * 84;
  const int iy = i >> 5, ix = i & 31;
  char* pwc = (char*)&pbuf[w][0];
  const int swz = (i15 & 7) << 4;

  // per-lane bx precompute (jx = hi*16 + g*4 + r, fixed all kernel)
  int bx8[2][4];
#pragma unroll
  for (int hi = 0; hi < 2; ++hi)
#pragma unroll
    for (int r = 0; r < 4; ++r) bx8[hi][r] = (int)pwx4s[ix - (hi * 16 + g * 4 + r) + 31];

  f32x4 oacc[4] = {};
  float psum = 0.f;

  // pipeline prologue: tile 0 K/V/by
  s16x8 kfA[4][2], vfA[4][2], kfB[4][2], vfB[4][2];
  int by0A, by1A, by0B, by1B;
#pragma unroll
  for (int jc = 0; jc < 4; ++jc) {
    const short* kr = Kb_h + (size_t)(jc * 16 + i15) * 64 + g * 8;
    kfA[jc][0] = *(const s16x8*)(kr);
    kfA[jc][1] = *(const s16x8*)(kr + 32);
  }
#pragma unroll
  for (int nc = 0; nc < 4; ++nc) {
    const short* vr = Vb_h + (size_t)(nc * 16 + i15) * NFULL + g * 8;
    vfA[nc][0] = *(const s16x8*)(vr);
    vfA[nc][1] = *(const s16x8*)(vr + 32);
  }
  by0A = (int)pwy9s[iy + 31];
  by1A = (int)pwy9s[iy + 30];

  for (int t2 = 0; t2 < 8; ++t2) {
    const int j0 = t2 * 128;
    ATTN_STEP(j0, j0 + 64, kfA, vfA, kfB, vfB, by0A, by1A, by0B, by1B)
    ATTN_STEP(j0 + 64, j0 + 128, kfB, vfB, kfA, vfA, by0B, by1B, by0A, by1A)
  }

  // row sum across the 4 lanes sharing a row
  psum += __shfl_xor(psum, 16);
  psum += __shfl_xor(psum, 32);
  const float rn = 1.0f / psum;

  // tv-bucket term straight from global (broadcast-friendly, L1/L2 resident)
  float tva[4][4] = {};
  for (int c1 = 0; c1 < 81; ++c1) {
    float wv = wbf[rowi * 81 + c1];
#pragma unroll
    for (int nc = 0; nc < 4; ++nc) {
      float4 t4 = *(const float4*)(tv + c1 * 64 + nc * 16 + g * 4);
      tva[nc][0] = fmaf(wv, t4.x, tva[nc][0]);
      tva[nc][1] = fmaf(wv, t4.y, tva[nc][1]);
      tva[nc][2] = fmaf(wv, t4.z, tva[nc][2]);
      tva[nc][3] = fmaf(wv, t4.w, tva[nc][3]);
    }
  }

  short* ob = (short*)o + ((size_t)b * NFULL + i) * CDIM + h * 64;
#pragma unroll
  for (int nc = 0; nc < 4; ++nc) {
    s16x4 o4;
#pragma unroll
    for (int r = 0; r < 4; ++r) o4[r] = (short)f2b((oacc[nc][r] + tva[nc][r]) * rn);
    *(s16x4*)(ob + nc * 16 + g * 4) = o4;
  }
}

// ---------------- launch ----------------
extern "C" void kernel_launch(void* const* d_in, const int* in_sizes, int n_in,
                              void* d_out, int out_size, void* d_ws, size_t ws_size,
                              hipStream_t stream) {
  (void)in_sizes; (void)n_in; (void)out_size; (void)ws_size;
  const float* x0 = (const float*)d_in[0];
  const float* x1 = (const float*)d_in[1];
  const float* ln00_g = (const float*)d_in[2];
  const float* ln00_b = (const float*)d_in[3];
  const float* ln01_g = (const float*)d_in[4];
  const float* ln01_b = (const float*)d_in[5];
  const float* ln10_g = (const float*)d_in[6];
  const float* ln10_b = (const float*)d_in[7];
  const float* ln11_g = (const float*)d_in[8];
  const float* ln11_b = (const float*)d_in[9];
  const float* w_qkv0 = (const float*)d_in[10];
  const float* b_qkv0 = (const float*)d_in[11];
  const float* w_qkv1 = (const float*)d_in[12];
  const float* b_qkv1 = (const float*)d_in[13];
  const float* w_proj = (const float*)d_in[14];
  const float* b_proj = (const float*)d_in[15];
  const float* table_q = (const float*)d_in[16];
  const float* table_k = (const float*)d_in[17];
  const float* table_v = (const float*)d_in[18];
  const float* w_fc1_0 = (const float*)d_in[19];
  const float* b_fc1_0 = (const float*)d_in[20];
  const float* w_fc2_0 = (const float*)d_in[21];
  const float* b_fc2_0 = (const float*)d_in[22];
  const float* w_fc1_1 = (const float*)d_in[23];
  const float* b_fc1_1 = (const float*)d_in[24];
  const float* w_fc2_1 = (const float*)d_in[25];
  const float* b_fc2_1 = (const float*)d_in[26];

  char* base = (char*)d_ws;
  short* qkvb0 = (short*)(base + 0);              // 12.6 MB
  short* qkvb1 = (short*)(base + 12582912);       // 12.6 MB
  short* Qb0   = (short*)(base + 25165824);       // 4 MB each
  short* Kb0   = (short*)(base + 29360128);
  short* Vtb0  = (short*)(base + 33554432);
  short* Qb1   = (short*)(base + 37748736);
  short* Kb1   = (short*)(base + 41943040);
  short* Vtb1  = (short*)(base + 46137344);
  short* lkg   = (short*)(base + 50331648);       // 5.5 MB
  short* lqg   = (short*)(base + 55836672);       // 5.5 MB
  short* obuf  = (short*)(base + 61341696);       // 4 MB
  __hip_bfloat16* xnb = (__hip_bfloat16*)(base + 65536000);  // 4 MB
  __hip_bfloat16* wq0t  = (__hip_bfloat16*)(base + 69730304);
  __hip_bfloat16* wq1t  = (__hip_bfloat16*)(base + 71303168);
  __hip_bfloat16* wpt   = (__hip_bfloat16*)(base + 72876032);
  __hip_bfloat16* wf10t = (__hip_bfloat16*)(base + 73400320);
  __hip_bfloat16* wf20t = (__hip_bfloat16*)(base + 75497472);
  __hip_bfloat16* wf11t = (__hip_bfloat16*)(base + 77594624);
  __hip_bfloat16* wf21t = (__hip_bfloat16*)(base + 79691776); // end ~81.8 MB
  short* hbufb = (short*)(base + 0);              // MLP hidden aliases dead qkvb
  float* dout0 = (float*)d_out;
  float* dout1 = dout0 + (size_t)4 * 1024 * 512;

  const int M = 4096;

  wtrans_kernel<<<dim3(48, 16), dim3(32, 8), 0, stream>>>(w_qkv0, wq0t, 512, 1536);
  wtrans_kernel<<<dim3(48, 16), dim3(32, 8), 0, stream>>>(w_qkv1, wq1t, 512, 1536);
  wtrans_kernel<<<dim3(16, 16), dim3(32, 8), 0, stream>>>(w_proj, wpt, 512, 512);
  wtrans_kernel<<<dim3(64, 16), dim3(32, 8), 0, stream>>>(w_fc1_0, wf10t, 512, 2048);
  wtrans_kernel<<<dim3(16, 64), dim3(32, 8), 0, stream>>>(w_fc2_0, wf20t, 2048, 512);
  wtrans_kernel<<<dim3(64, 16), dim3(32, 8), 0, stream>>>(w_fc1_1, wf11t, 512, 2048);
  wtrans_kernel<<<dim3(16, 64), dim3(32, 8), 0, stream>>>(w_fc2_1, wf21t, 2048, 512);

  ln_kernel<<<M, 256, 0, stream>>>(x0, ln00_g, ln00_b, xnb);
  gemm_bf16<0, 0, 1><<<dim3(12, 32), 256, 0, stream>>>((const short*)xnb, (const short*)wq0t,
                                                       b_qkv0, nullptr, qkvb0, M, 1536, 512);
  ln_kernel<<<M, 256, 0, stream>>>(x1, ln01_g, ln01_b, xnb);
  gemm_bf16<0, 0, 1><<<dim3(12, 32), 256, 0, stream>>>((const short*)xnb, (const short*)wq1t,
                                                       b_qkv1, nullptr, qkvb1, M, 1536, 512);

  prep_kernel<<<dim3(16, 4), 256, 0, stream>>>(qkvb0, Qb0, Kb0, Vtb0);
  prep_kernel<<<dim3(16, 4), 256, 0, stream>>>(qkvb1, Qb1, Kb1, Vtb1);

  // attention 0: q0 with k1/v1
  bias_gemm<<<dim3(8, 8, 4), 256, 0, stream>>>(Qb0, table_k, lkg, 1.0f);
  bias_gemm<<<dim3(8, 8, 4), 256, 0, stream>>>(Kb1, table_q, lqg, 0.125f);
  attn_mfma<<<dim3(16, 8, 4), 256, 0, stream>>>(Qb0, Kb1, Vtb1, lkg, lqg, table_v,
                                                (__hip_bfloat16*)obuf);
  gemm_bf16<0, 1, 0><<<dim3(4, 32), 256, 0, stream>>>(obuf, (const short*)wpt,
                                                      b_proj, x0, dout0, M, 512, 512);

  // attention 1: q1 with k0/v0
  bias_gemm<<<dim3(8, 8, 4), 256, 0, stream>>>(Qb1, table_k, lkg, 1.0f);
  bias_gemm<<<dim3(8, 8, 4), 256, 0, stream>>>(Kb0, table_q, lqg, 0.125f);
  attn_mfma<<<dim3(16, 8, 4), 256, 0, stream>>>(Qb1, Kb0, Vtb0, lkg, lqg, table_v,
                                                (__hip_bfloat16*)obuf);
  gemm_bf16<0, 1, 0><<<dim3(4, 32), 256, 0, stream>>>(obuf, (const short*)wpt,
                                                      b_proj, x1, dout1, M, 512, 512);

  // MLP 0
  ln_kernel<<<M, 256, 0, stream>>>(dout0, ln10_g, ln10_b, xnb);
  gemm_bf16<1, 0, 1><<<dim3(16, 32), 256, 0, stream>>>((const short*)xnb, (const short*)wf10t,
                                                       b_fc1_0, nullptr, hbufb, M, 2048, 512);
  gemm_bf16<0, 1, 0><<<dim3(4, 32), 256, 0, stream>>>(hbufb, (const short*)wf20t,
                                                      b_fc2_0, dout0, dout0, M, 512, 2048);

  // MLP 1
  ln_kernel<<<M, 256, 0, stream>>>(dout1, ln11_g, ln11_b, xnb);
  gemm_bf16<1, 0, 1><<<dim3(16, 32), 256, 0, stream>>>((const short*)xnb, (const short*)wf11t,
                                                       b_fc1_1, nullptr, hbufb, M, 2048, 512);
  gemm_bf16<0, 1, 0><<<dim3(4, 32), 256, 0, stream>>>(hbufb, (const short*)wf21t,
                                                      b_fc2_1, dout1, dout1, M, 512, 2048);
}